// Round 1
// baseline (258.830 us; speedup 1.0000x reference)
//
#include <hip/hip_runtime.h>

#define M_DIM 4096
#define N_DIM 4096
#define K_DIM 4096

typedef __attribute__((ext_vector_type(4))) int i32x4;
typedef __attribute__((ext_vector_type(16))) int i32x16;

typedef __attribute__((address_space(1))) const void GV;
typedef __attribute__((address_space(3))) void LV;

// ---------------------------------------------------------------------------
// Fused pre-kernel (unchanged from previous round).
//  blocks [0,1024):    hadamard (FWHT over 64 groups) + per-token absmax
//                      int8 quant; writes xq (i8) + sx (f32/token).
//  blocks [1024,2048): weight int8 recovery: per-row scale = absmax/127
//                      (exact inverse of setup-time per-channel QDQ);
//                      writes wq (i8) + sw (f32/row).
// ---------------------------------------------------------------------------
__global__ __launch_bounds__(256) void prequant_kernel(const float* __restrict__ x,
                                                       const float* __restrict__ w,
                                                       char* __restrict__ xq,
                                                       char* __restrict__ wq,
                                                       float* __restrict__ sx,
                                                       float* __restrict__ sw) {
  const int wave = threadIdx.x >> 6;
  const int lane = threadIdx.x & 63;

  if (blockIdx.x >= 1024) {
    // ---- weight row: recover integer codes exactly
    const int row = (blockIdx.x - 1024) * 4 + wave;
    const float* wp = w + (size_t)row * 4096;
    float4 v[16];
#pragma unroll
    for (int c = 0; c < 16; ++c) v[c] = *(const float4*)(wp + c * 256 + lane * 4);
    float amax = 0.f;
#pragma unroll
    for (int c = 0; c < 16; ++c)
      amax = fmaxf(amax, fmaxf(fmaxf(fabsf(v[c].x), fabsf(v[c].y)),
                               fmaxf(fabsf(v[c].z), fabsf(v[c].w))));
#pragma unroll
    for (int off = 32; off >= 1; off >>= 1) amax = fmaxf(amax, __shfl_xor(amax, off, 64));
    amax = fmaxf(amax, 1e-30f);
    const float inv = 127.0f / amax;  // w = iw*s with amax = 127*s  ->  w*inv = iw
    char* op = wq + (size_t)row * 4096;
#pragma unroll
    for (int c = 0; c < 16; ++c) {
      char4 o;
      o.x = (char)rintf(v[c].x * inv);
      o.y = (char)rintf(v[c].y * inv);
      o.z = (char)rintf(v[c].z * inv);
      o.w = (char)rintf(v[c].w * inv);
      *(char4*)(op + c * 256 + lane * 4) = o;
    }
    if (lane == 0) sw[row] = amax * (1.0f / 127.0f);
    return;
  }

  // ---- hadamard + per-token int8 quant
  const int tok = blockIdx.x * 4 + wave;
  const int gs = lane >> 4;  // quarter of g-space
  const int q = lane & 15;   // d-quad: d = q*4..q*4+3
  const float* xp = x + (size_t)tok * 4096;

  float4 v[16];  // lane holds g = gl*4+gs, gl=0..15, float4 over d
#pragma unroll
  for (int gl = 0; gl < 16; ++gl)
    v[gl] = *(const float4*)(xp + (gl * 4 + gs) * 64 + q * 4);

  // in-lane FWHT stages (g-bits 4,8,16,32 <=> gl-bits 1,2,4,8)
#pragma unroll
  for (int s = 1; s < 16; s <<= 1) {
#pragma unroll
    for (int i = 0; i < 16; ++i) {
      if ((i & s) == 0) {
        float4 a = v[i], b = v[i | s];
        v[i].x = a.x + b.x; v[i].y = a.y + b.y; v[i].z = a.z + b.z; v[i].w = a.w + b.w;
        v[i | s].x = a.x - b.x; v[i | s].y = a.y - b.y;
        v[i | s].z = a.z - b.z; v[i | s].w = a.w - b.w;
      }
    }
  }
  // cross-lane stages: g-bit 1 <=> lane^16, g-bit 2 <=> lane^32
#pragma unroll
  for (int st = 0; st < 2; ++st) {
    const int L = 16 << st;
    const bool hi = (lane & L) != 0;
#pragma unroll
    for (int i = 0; i < 16; ++i) {
      float4 t;
      t.x = __shfl_xor(v[i].x, L, 64);
      t.y = __shfl_xor(v[i].y, L, 64);
      t.z = __shfl_xor(v[i].z, L, 64);
      t.w = __shfl_xor(v[i].w, L, 64);
      if (hi) {
        v[i].x = t.x - v[i].x; v[i].y = t.y - v[i].y;
        v[i].z = t.z - v[i].z; v[i].w = t.w - v[i].w;
      } else {
        v[i].x += t.x; v[i].y += t.y; v[i].z += t.z; v[i].w += t.w;
      }
    }
  }

  float amax = 0.f;
#pragma unroll
  for (int i = 0; i < 16; ++i) {
    v[i].x *= 0.125f; v[i].y *= 0.125f; v[i].z *= 0.125f; v[i].w *= 0.125f;  // 1/sqrt(64)
    amax = fmaxf(amax, fmaxf(fmaxf(fabsf(v[i].x), fabsf(v[i].y)),
                             fmaxf(fabsf(v[i].z), fabsf(v[i].w))));
  }
#pragma unroll
  for (int off = 32; off >= 1; off >>= 1) amax = fmaxf(amax, __shfl_xor(amax, off, 64));

  const float s = fmaxf(amax * (1.0f / 127.0f), 1e-5f);  // reference clip
  const float inv = 1.0f / s;

  char* op = xq + (size_t)tok * 4096;
#pragma unroll
  for (int gl = 0; gl < 16; ++gl) {
    char4 o;
    o.x = (char)rintf(v[gl].x * inv);
    o.y = (char)rintf(v[gl].y * inv);
    o.z = (char)rintf(v[gl].z * inv);
    o.w = (char)rintf(v[gl].w * inv);
    *(char4*)(op + (gl * 4 + gs) * 64 + q * 4) = o;
  }
  if (lane == 0) sx[tok] = s;
}

// ---------------------------------------------------------------------------
// Int8 GEMM, pipelined: C[m][n] = sx[m]*sw[n]*(sum_k ix[m][k]*iw[n][k]) + b[n]
//
// 256x256 tile, BK=32, 8 waves (2M x 4N), each wave owns 128x64 = 4x2 frags
// of mfma_i32_32x32x32_i8. LDS = 4-deep ring of 16KB K-tiles (A 8KB + B 8KB)
// = 64KB static. Tile t+3 is staged (global_load_lds, 2 loads/thread) while
// tile t computes; the per-tile wait is a COUNTED s_waitcnt vmcnt(4) -- two
// tiles always in flight, never drained in the main loop (T3+T4). setprio(1)
// brackets the 8-MFMA cluster (T5). Raw s_barrier only -- no __syncthreads
// (which would emit the vmcnt(0) drain).
//
// LDS swizzle (T2, derived for 32B rows): 16B segment seg of row r lives at
// slot seg ^ ((r>>2)&1). Frag reads (32 lanes, 32 consecutive rows, same seg)
// then cover all 32 banks uniformly (8-row period): conflict-free.
// global_load_lds writes linearly (dest = tid*16), so the *global* source
// segment is pre-swizzled with the same involution (both-sides rule).
//
// Grid 256 = 1 block/CU; XCD swizzle: XCD c gets a 4bm x 8bn sub-grid so the
// per-K-slice working set (~192KB) is L2-resident per XCD.
// ---------------------------------------------------------------------------
__global__ __launch_bounds__(512, 2) void gemm_i8(const char* __restrict__ A,
                                                  const char* __restrict__ B,
                                                  const float* __restrict__ sx,
                                                  const float* __restrict__ sw,
                                                  const float* __restrict__ bias,
                                                  float* __restrict__ C) {
  __shared__ __align__(16) char sm[65536];  // 4 bufs x (A 8KB + B 8KB)

  const int tid = threadIdx.x;
  const int lane = tid & 63;
  const int wave = tid >> 6;
  const int wm = wave >> 2;   // 0..1
  const int wn = wave & 3;    // 0..3
  const int m32 = lane & 31;
  const int half = lane >> 5;

  // XCD-aware block swizzle: xcd(bid)=bid&7 (round-robin); XCD c covers
  // bm in [(c&3)*4,+4), bn in [(c>>2)*8,+8). Bijective over the 16x16 grid.
  const int bid = blockIdx.x;
  const int cx = bid & 7, ii = bid >> 3;
  const int bm = (cx & 3) * 4 + (ii >> 3);
  const int bn = (cx >> 2) * 8 + (ii & 7);

  // ---- staging: thread tid stages 16B of A and 16B of B per K-tile.
  //      LDS dest is linear (tid*16): row = tid>>1, slot = tid&1.
  //      Fetch global seg = slot ^ ((row>>2)&1)  [involution]
  const int strow = tid >> 1;
  const int stseg = ((tid & 1) ^ ((tid >> 3) & 1)) << 4;
  const char* gA = A + (size_t)(bm * 256 + strow) * K_DIM + stseg;
  const char* gB = B + (size_t)(bn * 256 + strow) * K_DIM + stseg;

  // ---- fragment read offsets (buffer-local): addr = row*32 + swz(seg)*16
  auto lof = [&](int row) { return row * 32 + ((half ^ ((row >> 2) & 1)) << 4); };
  const int aoff0 = lof(wm * 128 + 0 + m32);
  const int aoff1 = lof(wm * 128 + 32 + m32);
  const int aoff2 = lof(wm * 128 + 64 + m32);
  const int aoff3 = lof(wm * 128 + 96 + m32);
  const int boff0 = 8192 + lof(wn * 64 + 0 + m32);
  const int boff1 = 8192 + lof(wn * 64 + 32 + m32);

  i32x16 acc[4][2];
#pragma unroll
  for (int i = 0; i < 4; ++i)
#pragma unroll
    for (int j = 0; j < 2; ++j)
#pragma unroll
      for (int r = 0; r < 16; ++r) acc[i][j][r] = 0;

  // ---- prologue: stage tiles 0,1,2 (6 loads/thread); guard tile 0.
#pragma unroll
  for (int s = 0; s < 3; ++s) {
    char* ld = sm + s * 16384 + (tid << 4);
    const size_t ko = (size_t)s * 32;
    __builtin_amdgcn_global_load_lds((GV*)(gA + ko), (LV*)ld, 16, 0, 0);
    __builtin_amdgcn_global_load_lds((GV*)(gB + ko), (LV*)(ld + 8192), 16, 0, 0);
  }
  asm volatile("s_waitcnt vmcnt(4)" ::: "memory");  // tiles 1,2 stay in flight
  __builtin_amdgcn_s_barrier();

  // Per tile t: [stage t+3] -> 6 ds_read_b128 -> barrier -> lgkmcnt(0) ->
  // setprio(1) 8x MFMA setprio(0) -> counted vmcnt (guards tile t+1) ->
  // barrier. Buffer (t+3)&3 was last read by tile t-1, whose reads all
  // completed before its end-barrier -> no WAR hazard on the stage.
#define KTILE(T, DOSTAGE, TAILWAIT)                                                   \
  {                                                                                   \
    const char* bufp = sm + ((T) & 3) * 16384;                                        \
    if (DOSTAGE) {                                                                    \
      char* ld = sm + (((T) + 3) & 3) * 16384 + (tid << 4);                           \
      const size_t ko = (size_t)((T) + 3) * 32;                                       \
      __builtin_amdgcn_global_load_lds((GV*)(gA + ko), (LV*)ld, 16, 0, 0);            \
      __builtin_amdgcn_global_load_lds((GV*)(gB + ko), (LV*)(ld + 8192), 16, 0, 0);   \
    }                                                                                 \
    const i32x4 a0 = *(const i32x4*)(bufp + aoff0);                                   \
    const i32x4 a1 = *(const i32x4*)(bufp + aoff1);                                   \
    const i32x4 a2 = *(const i32x4*)(bufp + aoff2);                                   \
    const i32x4 a3 = *(const i32x4*)(bufp + aoff3);                                   \
    const i32x4 b0 = *(const i32x4*)(bufp + boff0);                                   \
    const i32x4 b1 = *(const i32x4*)(bufp + boff1);                                   \
    __builtin_amdgcn_s_barrier();                                                     \
    asm volatile("s_waitcnt lgkmcnt(0)" ::: "memory");                                \
    __builtin_amdgcn_sched_barrier(0);                                                \
    __builtin_amdgcn_s_setprio(1);                                                    \
    acc[0][0] = __builtin_amdgcn_mfma_i32_32x32x32_i8(a0, b0, acc[0][0], 0, 0, 0);    \
    acc[0][1] = __builtin_amdgcn_mfma_i32_32x32x32_i8(a0, b1, acc[0][1], 0, 0, 0);    \
    acc[1][0] = __builtin_amdgcn_mfma_i32_32x32x32_i8(a1, b0, acc[1][0], 0, 0, 0);    \
    acc[1][1] = __builtin_amdgcn_mfma_i32_32x32x32_i8(a1, b1, acc[1][1], 0, 0, 0);    \
    acc[2][0] = __builtin_amdgcn_mfma_i32_32x32x32_i8(a2, b0, acc[2][0], 0, 0, 0);    \
    acc[2][1] = __builtin_amdgcn_mfma_i32_32x32x32_i8(a2, b1, acc[2][1], 0, 0, 0);    \
    acc[3][0] = __builtin_amdgcn_mfma_i32_32x32x32_i8(a3, b0, acc[3][0], 0, 0, 0);    \
    acc[3][1] = __builtin_amdgcn_mfma_i32_32x32x32_i8(a3, b1, acc[3][1], 0, 0, 0);    \
    __builtin_amdgcn_s_setprio(0);                                                    \
    asm volatile("s_waitcnt " TAILWAIT ::: "memory");                                 \
    __builtin_amdgcn_s_barrier();                                                     \
  }

#pragma unroll 1
  for (int t = 0; t < 125; ++t) {
    KTILE(t, 1, "vmcnt(4)");  // stages t+3 = 3..127
  }
  KTILE(125, 0, "vmcnt(2)");  // only tile 127 may remain in flight
  KTILE(126, 0, "vmcnt(0)");
  KTILE(127, 0, "vmcnt(0)");  // trivially satisfied
#undef KTILE

  // ---- epilogue: C/D layout col=lane&31, row=(r&3)+8*(r>>2)+4*(lane>>5)
  const int col0 = bn * 256 + wn * 64 + m32;
  const float swv0 = sw[col0];
  const float swv1 = sw[col0 + 32];
  const float bv0 = bias[col0];
  const float bv1 = bias[col0 + 32];

#pragma unroll
  for (int fm = 0; fm < 4; ++fm) {
    const int rbase = bm * 256 + wm * 128 + fm * 32 + 4 * half;
    float sxv[16];
#pragma unroll
    for (int r = 0; r < 16; ++r) sxv[r] = sx[rbase + (r & 3) + 8 * (r >> 2)];
#pragma unroll
    for (int fn = 0; fn < 2; ++fn) {
      const int colg = col0 + fn * 32;
      const float swb = fn ? swv1 : swv0;
      const float bvb = fn ? bv1 : bv0;
#pragma unroll
      for (int r = 0; r < 16; ++r) {
        const int rowg = rbase + (r & 3) + 8 * (r >> 2);
        C[(size_t)rowg * N_DIM + colg] = (float)acc[fm][fn][r] * (sxv[r] * swb) + bvb;
      }
    }
  }
}

// ---------------------------------------------------------------------------
extern "C" void kernel_launch(void* const* d_in, const int* in_sizes, int n_in,
                              void* d_out, int out_size, void* d_ws, size_t ws_size,
                              hipStream_t stream) {
  const float* x = (const float*)d_in[0];     // (2,2048,4096) fp32
  const float* w = (const float*)d_in[1];     // (4096,4096) fp32 (pre-quantized)
  const float* bias = (const float*)d_in[2];  // (4096,) fp32

  char* xq = (char*)d_ws;                                   // 16 MB i8
  char* wq = xq + (size_t)M_DIM * K_DIM;                    // 16 MB i8
  float* sx = (float*)(wq + (size_t)N_DIM * K_DIM);         // 16 KB
  float* sw = sx + M_DIM;                                   // 16 KB
  float* out = (float*)d_out;

  prequant_kernel<<<2048, 256, 0, stream>>>(x, w, xq, wq, sx, sw);

  gemm_i8<<<dim3(256), dim3(512), 0, stream>>>(xq, wq, sx, sw, bias, out);
}

// Round 2
// 257.180 us; speedup vs baseline: 1.0064x; 1.0064x over previous
//
#include <hip/hip_runtime.h>

#define M_DIM 4096
#define N_DIM 4096
#define K_DIM 4096

typedef __attribute__((ext_vector_type(4))) int i32x4;
typedef __attribute__((ext_vector_type(16))) int i32x16;

typedef __attribute__((address_space(1))) const void GV;
typedef __attribute__((address_space(3))) void LV;

// ---------------------------------------------------------------------------
// Fused pre-kernel (unchanged).
//  blocks [0,1024):    hadamard (FWHT over 64 groups) + per-token absmax
//                      int8 quant; writes xq (i8) + sx (f32/token).
//  blocks [1024,2048): weight int8 recovery: per-row scale = absmax/127;
//                      writes wq (i8) + sw (f32/row).
// ---------------------------------------------------------------------------
__global__ __launch_bounds__(256) void prequant_kernel(const float* __restrict__ x,
                                                       const float* __restrict__ w,
                                                       char* __restrict__ xq,
                                                       char* __restrict__ wq,
                                                       float* __restrict__ sx,
                                                       float* __restrict__ sw) {
  const int wave = threadIdx.x >> 6;
  const int lane = threadIdx.x & 63;

  if (blockIdx.x >= 1024) {
    const int row = (blockIdx.x - 1024) * 4 + wave;
    const float* wp = w + (size_t)row * 4096;
    float4 v[16];
#pragma unroll
    for (int c = 0; c < 16; ++c) v[c] = *(const float4*)(wp + c * 256 + lane * 4);
    float amax = 0.f;
#pragma unroll
    for (int c = 0; c < 16; ++c)
      amax = fmaxf(amax, fmaxf(fmaxf(fabsf(v[c].x), fabsf(v[c].y)),
                               fmaxf(fabsf(v[c].z), fabsf(v[c].w))));
#pragma unroll
    for (int off = 32; off >= 1; off >>= 1) amax = fmaxf(amax, __shfl_xor(amax, off, 64));
    amax = fmaxf(amax, 1e-30f);
    const float inv = 127.0f / amax;
    char* op = wq + (size_t)row * 4096;
#pragma unroll
    for (int c = 0; c < 16; ++c) {
      char4 o;
      o.x = (char)rintf(v[c].x * inv);
      o.y = (char)rintf(v[c].y * inv);
      o.z = (char)rintf(v[c].z * inv);
      o.w = (char)rintf(v[c].w * inv);
      *(char4*)(op + c * 256 + lane * 4) = o;
    }
    if (lane == 0) sw[row] = amax * (1.0f / 127.0f);
    return;
  }

  const int tok = blockIdx.x * 4 + wave;
  const int gs = lane >> 4;
  const int q = lane & 15;
  const float* xp = x + (size_t)tok * 4096;

  float4 v[16];
#pragma unroll
  for (int gl = 0; gl < 16; ++gl)
    v[gl] = *(const float4*)(xp + (gl * 4 + gs) * 64 + q * 4);

#pragma unroll
  for (int s = 1; s < 16; s <<= 1) {
#pragma unroll
    for (int i = 0; i < 16; ++i) {
      if ((i & s) == 0) {
        float4 a = v[i], b = v[i | s];
        v[i].x = a.x + b.x; v[i].y = a.y + b.y; v[i].z = a.z + b.z; v[i].w = a.w + b.w;
        v[i | s].x = a.x - b.x; v[i | s].y = a.y - b.y;
        v[i | s].z = a.z - b.z; v[i | s].w = a.w - b.w;
      }
    }
  }
#pragma unroll
  for (int st = 0; st < 2; ++st) {
    const int L = 16 << st;
    const bool hi = (lane & L) != 0;
#pragma unroll
    for (int i = 0; i < 16; ++i) {
      float4 t;
      t.x = __shfl_xor(v[i].x, L, 64);
      t.y = __shfl_xor(v[i].y, L, 64);
      t.z = __shfl_xor(v[i].z, L, 64);
      t.w = __shfl_xor(v[i].w, L, 64);
      if (hi) {
        v[i].x = t.x - v[i].x; v[i].y = t.y - v[i].y;
        v[i].z = t.z - v[i].z; v[i].w = t.w - v[i].w;
      } else {
        v[i].x += t.x; v[i].y += t.y; v[i].z += t.z; v[i].w += t.w;
      }
    }
  }

  float amax = 0.f;
#pragma unroll
  for (int i = 0; i < 16; ++i) {
    v[i].x *= 0.125f; v[i].y *= 0.125f; v[i].z *= 0.125f; v[i].w *= 0.125f;
    amax = fmaxf(amax, fmaxf(fmaxf(fabsf(v[i].x), fabsf(v[i].y)),
                             fmaxf(fabsf(v[i].z), fabsf(v[i].w))));
  }
#pragma unroll
  for (int off = 32; off >= 1; off >>= 1) amax = fmaxf(amax, __shfl_xor(amax, off, 64));

  const float s = fmaxf(amax * (1.0f / 127.0f), 1e-5f);
  const float inv = 1.0f / s;

  char* op = xq + (size_t)tok * 4096;
#pragma unroll
  for (int gl = 0; gl < 16; ++gl) {
    char4 o;
    o.x = (char)rintf(v[gl].x * inv);
    o.y = (char)rintf(v[gl].y * inv);
    o.z = (char)rintf(v[gl].z * inv);
    o.w = (char)rintf(v[gl].w * inv);
    *(char4*)(op + (gl * 4 + gs) * 64 + q * 4) = o;
  }
  if (lane == 0) sx[tok] = s;
}

// ---------------------------------------------------------------------------
// Int8 GEMM — faithful i8 port of the verified 8-phase 256^2 template (m201).
//
// BM=BN=256, BK=128 i8 (128-BYTE K-rows: byte-identical to the bf16 BK=64
// template geometry). 512 thr, 8 waves (2M x 4N), per-wave 128x64 = 4x2 frags
// of mfma_i32_32x32x32_i8. LDS 128KB: 2 buffers x [A(2x16KB halves) |
// B(2x16KB halves)]. Halves are M/N-INTERLEAVED so one phase consumes exactly
// one A-half + one B-half:
//   A-half h  = tile rows {h*64..h*64+63} u {128+h*64..}   (LDS rows 0-127)
//   B-half h  = tile rows with (row>>5)&1 == h
// Phase (Mh,Nh): 12 ds_read_b128 (8 A-frag + 4 B-frag, full K=128) || stage
// ONE half of tile t+1 (2 x global_load_lds 16B) -> lgkmcnt(8) -> COUNTED
// vmcnt(4) (2 stage-pairs in flight, never drained) -> s_barrier ->
// lgkmcnt(0) -> setprio(1) 8x MFMA setprio(0) -> s_barrier.
//
// Stage order Ah0,Bh0,Bh1,Ah1 vs consume order (A0B0)(A0B1)(A1B0)(A1B1):
// every half is staged >=3 phases before first consumption (~1700 cyc >
// 900-cyc HBM latency); vmcnt(4) at phase P forces completion of the pair
// from P-2, i.e. one phase before any consumer's ds_reads (propagated
// cross-wave by the barriers). WAR: stage@P overwrites a region last read
// 4+ phases (several barriers) earlier. Prologue stages tile0's 4 halves +
// vmcnt(4) == exact steady-state outstanding pattern; tail tile drains
// vmcnt 2 -> 0.
//
// Swizzle (both-sides, rule-21 pattern c): 128B rows, slot = seg ^ (row&7).
// Reads: 32 lanes x 32 consecutive rows, fixed seg -> slots cycle all 8 ->
// all 32 banks. Stage: linear LDS dest (tid*16, rows tid>>3 / +64), global
// source segment pre-swizzled with the same involution ((tid&7)^(row&7)).
// ---------------------------------------------------------------------------
__global__ __launch_bounds__(512, 2) void gemm_i8(const char* __restrict__ A,
                                                  const char* __restrict__ B,
                                                  const float* __restrict__ sx,
                                                  const float* __restrict__ sw,
                                                  const float* __restrict__ bias,
                                                  float* __restrict__ C) {
  __shared__ __align__(16) char sm[131072];

  const int tid = threadIdx.x;
  const int lane = tid & 63;
  const int wave = tid >> 6;
  const int wm = wave >> 2;   // 0..1
  const int wn = wave & 3;    // 0..3
  const int m32 = lane & 31;
  const int half = lane >> 5;

  // XCD-aware swizzle over the 16x16 block grid (bijective).
  const int bid = blockIdx.x;
  const int cx = bid & 7, ii = bid >> 3;
  const int bm = (cx & 3) * 4 + (ii >> 3);
  const int bn = (cx >> 2) * 8 + (ii & 7);

  // ---- staging bases: thread covers LDS rows r and r+64 of a half, slot tid&7.
  const int r = tid >> 3;                       // 0..63
  const int goff = ((tid & 7) ^ (r & 7)) << 4;  // inverse-swizzled K-segment
  const char* gA0 = A + (size_t)(bm * 256 + r) * K_DIM + goff;
  const char* gB0 = B + (size_t)(bn * 256 + ((r >> 5) << 6) + (r & 31)) * K_DIM + goff;

  // A half H, k-byte KO:  src rows +H*64 (+128); dest BB + H*16K + tid*16 (+8192)
#define STAGE_A(BB, H, KO)                                                                     \
  {                                                                                            \
    char* d_ = sm + (BB) + (H)*16384 + (tid << 4);                                             \
    __builtin_amdgcn_global_load_lds((GV*)(gA0 + (size_t)(H)*64 * K_DIM + (KO)), (LV*)d_, 16,  \
                                     0, 0);                                                    \
    __builtin_amdgcn_global_load_lds((GV*)(gA0 + (size_t)(H)*64 * K_DIM + 128 * K_DIM + (KO)), \
                                     (LV*)(d_ + 8192), 16, 0, 0);                              \
  }
  // B half H: src rows +H*32 (+128); dest BB + 32768 + H*16K + tid*16 (+8192)
#define STAGE_B(BB, H, KO)                                                                     \
  {                                                                                            \
    char* d_ = sm + (BB) + 32768 + (H)*16384 + (tid << 4);                                     \
    __builtin_amdgcn_global_load_lds((GV*)(gB0 + (size_t)(H)*32 * K_DIM + (KO)), (LV*)d_, 16,  \
                                     0, 0);                                                    \
    __builtin_amdgcn_global_load_lds((GV*)(gB0 + (size_t)(H)*32 * K_DIM + 128 * K_DIM + (KO)), \
                                     (LV*)(d_ + 8192), 16, 0, 0);                              \
  }

  // ---- fragment read offsets (within a half): row*128 + (seg^(row&7))*16
  const int aRow = (wm * 64 + m32) * 128;           // A: + m*4096 for m-frag 1
  const int bRow = 32768 + (wn * 32 + m32) * 128;   // B (incl. B-base)
  int sl[4];
#pragma unroll
  for (int kc = 0; kc < 4; ++kc) sl[kc] = ((kc * 2 + half) ^ (m32 & 7)) << 4;

  i32x16 acc[4][2];
#pragma unroll
  for (int i = 0; i < 4; ++i)
#pragma unroll
    for (int j = 0; j < 2; ++j)
#pragma unroll
      for (int rr = 0; rr < 16; ++rr) acc[i][j][rr] = 0;

#define PHASE(BB, MH, NH, STAGEBODY, WAITSTR)                                                  \
  {                                                                                            \
    const char* ap_ = sm + (BB) + (MH)*16384 + aRow;                                           \
    const char* bp_ = sm + (BB) + (NH)*16384 + bRow;                                           \
    i32x4 af[2][4], bf[4];                                                                     \
    _Pragma("unroll") for (int kc = 0; kc < 4; ++kc) {                                         \
      af[0][kc] = *(const i32x4*)(ap_ + sl[kc]);                                               \
      af[1][kc] = *(const i32x4*)(ap_ + 4096 + sl[kc]);                                        \
      bf[kc] = *(const i32x4*)(bp_ + sl[kc]);                                                  \
    }                                                                                          \
    STAGEBODY;                                                                                 \
    asm volatile("s_waitcnt lgkmcnt(8)" ::: "memory");                                         \
    asm volatile("s_waitcnt " WAITSTR ::: "memory");                                           \
    __builtin_amdgcn_s_barrier();                                                              \
    asm volatile("s_waitcnt lgkmcnt(0)" ::: "memory");                                         \
    __builtin_amdgcn_s_setprio(1);                                                             \
    _Pragma("unroll") for (int kc = 0; kc < 4; ++kc) {                                         \
      acc[(MH)*2 + 0][NH] =                                                                    \
          __builtin_amdgcn_mfma_i32_32x32x32_i8(af[0][kc], bf[kc], acc[(MH)*2 + 0][NH], 0, 0,  \
                                                0);                                            \
      acc[(MH)*2 + 1][NH] =                                                                    \
          __builtin_amdgcn_mfma_i32_32x32x32_i8(af[1][kc], bf[kc], acc[(MH)*2 + 1][NH], 0, 0,  \
                                                0);                                            \
    }                                                                                          \
    __builtin_amdgcn_s_setprio(0);                                                             \
    __builtin_amdgcn_s_barrier();                                                              \
  }

  // ---- prologue: tile 0's 4 halves, in the steady-state stage order.
  STAGE_A(0, 0, 0);
  STAGE_B(0, 0, 0);
  STAGE_B(0, 1, 0);
  STAGE_A(0, 1, 0);
  asm volatile("s_waitcnt vmcnt(4)" ::: "memory");  // Ah0,Bh0 done; Bh1,Ah1 in flight
  __builtin_amdgcn_s_barrier();

#pragma unroll 1
  for (int t = 0; t < 31; ++t) {
    const int BB = (t & 1) << 16;
    const int SB = ((t + 1) & 1) << 16;
    const int ko = (t + 1) * 128;
    PHASE(BB, 0, 0, STAGE_A(SB, 0, ko), "vmcnt(4)");
    PHASE(BB, 0, 1, STAGE_B(SB, 0, ko), "vmcnt(4)");
    PHASE(BB, 1, 0, STAGE_B(SB, 1, ko), "vmcnt(4)");
    PHASE(BB, 1, 1, STAGE_A(SB, 1, ko), "vmcnt(4)");
  }
  {
    const int BB = 1 << 16;  // tile 31
    PHASE(BB, 0, 0, , "vmcnt(2)");
    PHASE(BB, 0, 1, , "vmcnt(0)");
    PHASE(BB, 1, 0, , "vmcnt(0)");
    PHASE(BB, 1, 1, , "vmcnt(0)");
  }
#undef PHASE
#undef STAGE_A
#undef STAGE_B

  // ---- epilogue: C/D layout col=lane&31, row=(r&3)+8*(r>>2)+4*(lane>>5)
  const int col0 = bn * 256 + wn * 64 + m32;
  const float swv0 = sw[col0];
  const float swv1 = sw[col0 + 32];
  const float bv0 = bias[col0];
  const float bv1 = bias[col0 + 32];

#pragma unroll
  for (int fm = 0; fm < 4; ++fm) {
    const int rbase = bm * 256 + wm * 128 + fm * 32 + 4 * half;
    float sxv[16];
#pragma unroll
    for (int rr = 0; rr < 16; ++rr) sxv[rr] = sx[rbase + (rr & 3) + 8 * (rr >> 2)];
#pragma unroll
    for (int fn = 0; fn < 2; ++fn) {
      const int colg = col0 + fn * 32;
      const float swb = fn ? swv1 : swv0;
      const float bvb = fn ? bv1 : bv0;
#pragma unroll
      for (int rr = 0; rr < 16; ++rr) {
        const int rowg = rbase + (rr & 3) + 8 * (rr >> 2);
        C[(size_t)rowg * N_DIM + colg] = (float)acc[fm][fn][rr] * (sxv[rr] * swb) + bvb;
      }
    }
  }
}

// ---------------------------------------------------------------------------
extern "C" void kernel_launch(void* const* d_in, const int* in_sizes, int n_in,
                              void* d_out, int out_size, void* d_ws, size_t ws_size,
                              hipStream_t stream) {
  const float* x = (const float*)d_in[0];     // (2,2048,4096) fp32
  const float* w = (const float*)d_in[1];     // (4096,4096) fp32 (pre-quantized)
  const float* bias = (const float*)d_in[2];  // (4096,) fp32

  char* xq = (char*)d_ws;                                   // 16 MB i8
  char* wq = xq + (size_t)M_DIM * K_DIM;                    // 16 MB i8
  float* sx = (float*)(wq + (size_t)N_DIM * K_DIM);         // 16 KB
  float* sw = sx + M_DIM;                                   // 16 KB
  float* out = (float*)d_out;

  prequant_kernel<<<2048, 256, 0, stream>>>(x, w, xq, wq, sx, sw);

  gemm_i8<<<dim3(256), dim3(512), 0, stream>>>(xq, wq, sx, sw, bias, out);
}

// Round 3
// 244.093 us; speedup vs baseline: 1.0604x; 1.0536x over previous
//
#include <hip/hip_runtime.h>

#define M_DIM 4096
#define N_DIM 4096
#define K_DIM 4096

typedef __attribute__((ext_vector_type(4))) int i32x4;
typedef __attribute__((ext_vector_type(16))) int i32x16;

typedef __attribute__((address_space(1))) const void GV;
typedef __attribute__((address_space(3))) void LV;

// ---------------------------------------------------------------------------
// Fused pre-kernel (unchanged).
//  blocks [0,1024):    hadamard (FWHT over 64 groups) + per-token absmax
//                      int8 quant; writes xq (i8) + sx (f32/token).
//  blocks [1024,2048): weight int8 recovery: per-row scale = absmax/127;
//                      writes wq (i8) + sw (f32/row).
// ---------------------------------------------------------------------------
__global__ __launch_bounds__(256) void prequant_kernel(const float* __restrict__ x,
                                                       const float* __restrict__ w,
                                                       char* __restrict__ xq,
                                                       char* __restrict__ wq,
                                                       float* __restrict__ sx,
                                                       float* __restrict__ sw) {
  const int wave = threadIdx.x >> 6;
  const int lane = threadIdx.x & 63;

  if (blockIdx.x >= 1024) {
    const int row = (blockIdx.x - 1024) * 4 + wave;
    const float* wp = w + (size_t)row * 4096;
    float4 v[16];
#pragma unroll
    for (int c = 0; c < 16; ++c) v[c] = *(const float4*)(wp + c * 256 + lane * 4);
    float amax = 0.f;
#pragma unroll
    for (int c = 0; c < 16; ++c)
      amax = fmaxf(amax, fmaxf(fmaxf(fabsf(v[c].x), fabsf(v[c].y)),
                               fmaxf(fabsf(v[c].z), fabsf(v[c].w))));
#pragma unroll
    for (int off = 32; off >= 1; off >>= 1) amax = fmaxf(amax, __shfl_xor(amax, off, 64));
    amax = fmaxf(amax, 1e-30f);
    const float inv = 127.0f / amax;
    char* op = wq + (size_t)row * 4096;
#pragma unroll
    for (int c = 0; c < 16; ++c) {
      char4 o;
      o.x = (char)rintf(v[c].x * inv);
      o.y = (char)rintf(v[c].y * inv);
      o.z = (char)rintf(v[c].z * inv);
      o.w = (char)rintf(v[c].w * inv);
      *(char4*)(op + c * 256 + lane * 4) = o;
    }
    if (lane == 0) sw[row] = amax * (1.0f / 127.0f);
    return;
  }

  const int tok = blockIdx.x * 4 + wave;
  const int gs = lane >> 4;
  const int q = lane & 15;
  const float* xp = x + (size_t)tok * 4096;

  float4 v[16];
#pragma unroll
  for (int gl = 0; gl < 16; ++gl)
    v[gl] = *(const float4*)(xp + (gl * 4 + gs) * 64 + q * 4);

#pragma unroll
  for (int s = 1; s < 16; s <<= 1) {
#pragma unroll
    for (int i = 0; i < 16; ++i) {
      if ((i & s) == 0) {
        float4 a = v[i], b = v[i | s];
        v[i].x = a.x + b.x; v[i].y = a.y + b.y; v[i].z = a.z + b.z; v[i].w = a.w + b.w;
        v[i | s].x = a.x - b.x; v[i | s].y = a.y - b.y;
        v[i | s].z = a.z - b.z; v[i | s].w = a.w - b.w;
      }
    }
  }
#pragma unroll
  for (int st = 0; st < 2; ++st) {
    const int L = 16 << st;
    const bool hi = (lane & L) != 0;
#pragma unroll
    for (int i = 0; i < 16; ++i) {
      float4 t;
      t.x = __shfl_xor(v[i].x, L, 64);
      t.y = __shfl_xor(v[i].y, L, 64);
      t.z = __shfl_xor(v[i].z, L, 64);
      t.w = __shfl_xor(v[i].w, L, 64);
      if (hi) {
        v[i].x = t.x - v[i].x; v[i].y = t.y - v[i].y;
        v[i].z = t.z - v[i].z; v[i].w = t.w - v[i].w;
      } else {
        v[i].x += t.x; v[i].y += t.y; v[i].z += t.z; v[i].w += t.w;
      }
    }
  }

  float amax = 0.f;
#pragma unroll
  for (int i = 0; i < 16; ++i) {
    v[i].x *= 0.125f; v[i].y *= 0.125f; v[i].z *= 0.125f; v[i].w *= 0.125f;
    amax = fmaxf(amax, fmaxf(fmaxf(fabsf(v[i].x), fabsf(v[i].y)),
                             fmaxf(fabsf(v[i].z), fabsf(v[i].w))));
  }
#pragma unroll
  for (int off = 32; off >= 1; off >>= 1) amax = fmaxf(amax, __shfl_xor(amax, off, 64));

  const float s = fmaxf(amax * (1.0f / 127.0f), 1e-5f);
  const float inv = 1.0f / s;

  char* op = xq + (size_t)tok * 4096;
#pragma unroll
  for (int gl = 0; gl < 16; ++gl) {
    char4 o;
    o.x = (char)rintf(v[gl].x * inv);
    o.y = (char)rintf(v[gl].y * inv);
    o.z = (char)rintf(v[gl].z * inv);
    o.w = (char)rintf(v[gl].w * inv);
    *(char4*)(op + (gl * 4 + gs) * 64 + q * 4) = o;
  }
  if (lane == 0) sx[tok] = s;
}

// ---------------------------------------------------------------------------
// Int8 GEMM, AITER-shaped K-loop: ONE barrier + ONE counted vmcnt per K-tile,
// minimum LDS reads (every fragment read exactly once).
//
// BM=BN=256, BK=64 i8 (64-byte K-rows, 32KB/tile). 512 thr, 8 waves (2M x 4N),
// per-wave 128x64 = 4x2 frags of mfma_i32_32x32x32_i8 (acc 128 VGPR).
// Per K-tile per wave: 12 ds_read_b128 (8 A + 4 B, each frag ONCE) feeding
// 16 MFMA -> per-CU: mfma 1171 cyc vs LDS ~768 cyc, overlappable because
// there are NO intra-tile barriers: the compiler's counted lgkmcnt + 2-wave/
// SIMD slip interleave reads under MFMA (m114). ~32 MFMA-issues/SIMD between
// barriers = AITER's hand-asm density (s02).
//
// LDS: 3-buffer ring (3 x 32KB = 96KB). During tile t we stage tile t+2
// (4 x global_load_lds 16B per thread) into the buffer holding t-1's data
// (safe: boundary barrier t-1->t ended all reads of it). Gate at end of tile
// t: vmcnt(4) = "t+1's 4 loads landed, t+2's 4 still in flight" -- counted,
// never drained until the 2-tile tail; issue->gate distance = one full tile
// (~2000 cyc > 900-cyc HBM latency). Cross-wave visibility: own-wave vmcnt +
// the boundary s_barrier; sched_barrier(0) after it pins reads/stages from
// hoisting above (race protection).
//
// Swizzle (64B rows, both-sides): 16B seg s of row r lives in slot
// s ^ ((r>>1)&3). Frag read (32 lanes, consecutive rows, fixed seg):
// bank-base = 16*(r&1) + 4*slot cycles 8 distinct groups per 8 rows ->
// uniform spread. Stage: linear LDS dest (tid*16 -> row=tid>>2, slot=tid&3),
// global seg pre-swizzled with the same involution ((tid&3)^((tid>>3)&3)).
// ---------------------------------------------------------------------------
__global__ __launch_bounds__(512, 2) void gemm_i8(const char* __restrict__ A,
                                                  const char* __restrict__ B,
                                                  const float* __restrict__ sx,
                                                  const float* __restrict__ sw,
                                                  const float* __restrict__ bias,
                                                  float* __restrict__ C) {
  __shared__ __align__(16) char sm[98304];  // 3 x (A 16KB | B 16KB)

  const int tid = threadIdx.x;
  const int lane = tid & 63;
  const int wave = tid >> 6;
  const int wm = wave >> 2;   // 0..1  (M half: 128 rows)
  const int wn = wave & 3;    // 0..3  (N quarter: 64 cols)
  const int m32 = lane & 31;
  const int half = lane >> 5;

  // XCD-aware swizzle over the 16x16 block grid (bijective).
  const int bid = blockIdx.x;
  const int cx = bid & 7, ii = bid >> 3;
  const int bm = (cx & 3) * 4 + (ii >> 3);
  const int bn = (cx >> 2) * 8 + (ii & 7);

  // ---- staging: thread tid covers rows (tid>>2) and (tid>>2)+128 of A and B.
  //      LDS dest linear: row*64 + (tid&3)*16 == tid*16. Global segment
  //      pre-swizzled: seg = (tid&3) ^ (((tid>>2)>>1)&3) = (tid&3)^((tid>>3)&3).
  const int strow = tid >> 2;  // 0..127
  const int sseg = ((tid & 3) ^ ((tid >> 3) & 3)) << 4;
  const char* gA0 = A + (size_t)(bm * 256 + strow) * K_DIM + sseg;
  const char* gB0 = B + (size_t)(bn * 256 + strow) * K_DIM + sseg;

#define STAGE(BUFOFF, KO)                                                                \
  {                                                                                      \
    char* d_ = sm + (BUFOFF) + (tid << 4);                                               \
    __builtin_amdgcn_global_load_lds((GV*)(gA0 + (KO)), (LV*)d_, 16, 0, 0);              \
    __builtin_amdgcn_global_load_lds((GV*)(gA0 + 128 * (size_t)K_DIM + (KO)),            \
                                     (LV*)(d_ + 8192), 16, 0, 0);                        \
    __builtin_amdgcn_global_load_lds((GV*)(gB0 + (KO)), (LV*)(d_ + 16384), 16, 0, 0);    \
    __builtin_amdgcn_global_load_lds((GV*)(gB0 + 128 * (size_t)K_DIM + (KO)),            \
                                     (LV*)(d_ + 24576), 16, 0, 0);                       \
  }

  // ---- fragment read offsets: addr = region + row*64 + slot(kc)*16
  //      row = Wbase + fm*32 + m32; (row>>1)&3 == (m32>>1)&3 (fm*32, Wbase mult of 32)
  const int aBase = (wm * 128 + m32) * 64;           // + fm*2048
  const int bBase = 16384 + (wn * 64 + m32) * 64;    // + fn*2048
  int sl[2];
#pragma unroll
  for (int kc = 0; kc < 2; ++kc) sl[kc] = ((kc * 2 + half) ^ ((m32 >> 1) & 3)) << 4;

  i32x16 acc[4][2];
#pragma unroll
  for (int i = 0; i < 4; ++i)
#pragma unroll
    for (int j = 0; j < 2; ++j)
#pragma unroll
      for (int r = 0; r < 16; ++r) acc[i][j][r] = 0;

  // ---- prologue: stage tiles 0 and 1; gate tile 0; enter loop.
  STAGE(0, 0);
  STAGE(32768, 64);
  asm volatile("s_waitcnt vmcnt(4)" ::: "memory");  // tile 0 landed; tile 1 in flight
  __builtin_amdgcn_s_barrier();
  __builtin_amdgcn_sched_barrier(0);

  int o0 = 0, o1 = 32768, o2 = 65536;  // compute | resident-next | landing

#pragma unroll 1
  for (int t = 0; t < 64; ++t) {
    const char* bufp = sm + o0;

    // 12 ds_read_b128: every fragment of this K-tile exactly once.
    i32x4 af[2][4], bf[2][2];
#pragma unroll
    for (int kc = 0; kc < 2; ++kc) {
#pragma unroll
      for (int fm = 0; fm < 4; ++fm)
        af[kc][fm] = *(const i32x4*)(bufp + aBase + fm * 2048 + sl[kc]);
#pragma unroll
      for (int fn = 0; fn < 2; ++fn)
        bf[kc][fn] = *(const i32x4*)(bufp + bBase + fn * 2048 + sl[kc]);
    }

    if (t < 62) STAGE(o2, (size_t)(t + 2) * 64);  // tile t+2 into t-1's buffer

    __builtin_amdgcn_s_setprio(1);
#pragma unroll
    for (int kc = 0; kc < 2; ++kc)
#pragma unroll
      for (int fm = 0; fm < 4; ++fm)
#pragma unroll
        for (int fn = 0; fn < 2; ++fn)
          acc[fm][fn] =
              __builtin_amdgcn_mfma_i32_32x32x32_i8(af[kc][fm], bf[kc][fn], acc[fm][fn], 0, 0, 0);
    __builtin_amdgcn_s_setprio(0);

    if (t < 62) {
      asm volatile("s_waitcnt vmcnt(4)" ::: "memory");  // t+1 landed; t+2 in flight
    } else if (t == 62) {
      asm volatile("s_waitcnt vmcnt(0)" ::: "memory");  // tail: tile 63 landed
    }
    if (t < 63) {
      __builtin_amdgcn_s_barrier();
      __builtin_amdgcn_sched_barrier(0);
    }
    const int tmp = o0; o0 = o1; o1 = o2; o2 = tmp;
  }
#undef STAGE

  // ---- epilogue: C/D layout col=lane&31, row=(r&3)+8*(r>>2)+4*(lane>>5)
  const int col0 = bn * 256 + wn * 64 + m32;
  const float swv0 = sw[col0];
  const float swv1 = sw[col0 + 32];
  const float bv0 = bias[col0];
  const float bv1 = bias[col0 + 32];

#pragma unroll
  for (int fm = 0; fm < 4; ++fm) {
    const int rbase = bm * 256 + wm * 128 + fm * 32 + 4 * half;
    float sxv[16];
#pragma unroll
    for (int r = 0; r < 16; ++r) sxv[r] = sx[rbase + (r & 3) + 8 * (r >> 2)];
#pragma unroll
    for (int fn = 0; fn < 2; ++fn) {
      const int colg = col0 + fn * 32;
      const float swb = fn ? swv1 : swv0;
      const float bvb = fn ? bv1 : bv0;
#pragma unroll
      for (int r = 0; r < 16; ++r) {
        const int rowg = rbase + (r & 3) + 8 * (r >> 2);
        C[(size_t)rowg * N_DIM + colg] = (float)acc[fm][fn][r] * (sxv[r] * swb) + bvb;
      }
    }
  }
}

// ---------------------------------------------------------------------------
extern "C" void kernel_launch(void* const* d_in, const int* in_sizes, int n_in,
                              void* d_out, int out_size, void* d_ws, size_t ws_size,
                              hipStream_t stream) {
  const float* x = (const float*)d_in[0];     // (2,2048,4096) fp32
  const float* w = (const float*)d_in[1];     // (4096,4096) fp32 (pre-quantized)
  const float* bias = (const float*)d_in[2];  // (4096,) fp32

  char* xq = (char*)d_ws;                                   // 16 MB i8
  char* wq = xq + (size_t)M_DIM * K_DIM;                    // 16 MB i8
  float* sx = (float*)(wq + (size_t)N_DIM * K_DIM);         // 16 KB
  float* sw = sx + M_DIM;                                   // 16 KB
  float* out = (float*)d_out;

  prequant_kernel<<<2048, 256, 0, stream>>>(x, w, xq, wq, sx, sw);

  gemm_i8<<<dim3(256), dim3(512), 0, stream>>>(xq, wq, sx, sw, bias, out);
}